// Round 1
// baseline (277502.515 us; speedup 1.0000x reference)
//
#include <hip/hip_runtime.h>
#include <math.h>

#define NLS    4096   // 512 nodes * 8 stalk dims
#define NNODE  512
#define SDIM   8
#define KNN_K  5
#define MAXNBR 128
#define DIN    768

struct Ptrs {
  float* X;      // [2][NNODE][SDIM]
  int*   nn;     // [2][NNODE][KNN_K]
  int*   nbr;    // [2][NNODE][MAXNBR]
  int*   cnt;    // [2][NNODE]
  float* v;      // [2][NLS]   Householder vector, indexed by global row
  float* w;      // [2][NLS]   w = A_trail * v, indexed by global row
  float* ebuf;   // [2][NLS]   off-diagonal e[k]
  float* bta;    // [2][NLS]   beta[k]
  float* vtw;    // [2][NLS]   v^T w accumulators (must be zeroed)
  float* darr;   // [2][NLS]
  float* e2;     // [2][NLS]
  float* bounds; // [2][2]
  float* eigs;   // [2][NLS]
  float* A0;
  float* A1;
};

__device__ __forceinline__ float* matA(const Ptrs& p, int cloud) {
  return cloud == 0 ? p.A0 : p.A1;
}

// ---------------- zero helper ----------------
__global__ void zero_kernel(float* ptr, int n) {
  int i = blockIdx.x * 256 + threadIdx.x;
  if (i < n) ptr[i] = 0.f;
}

// ---------------- projection: X = emb @ W^T ----------------
__global__ void proj_kernel(Ptrs p, const float* q, const float* pe,
                            const float* ne, const float* W) {
  int idx = blockIdx.x * 256 + threadIdx.x;   // 2*512*8 = 8192
  if (idx >= 2 * NNODE * SDIM) return;
  int cloud = idx >> 12;          // 4096 per cloud
  int rem   = idx & 4095;
  int node  = rem >> 3, t = rem & 7;
  const float* src = (node < 256) ? (q + (size_t)node * DIN)
                                  : ((cloud == 0 ? pe : ne) + (size_t)(node - 256) * DIN);
  const float* wr = W + (size_t)t * DIN;
  float acc = 0.f;
  for (int i = 0; i < DIN; ++i) acc += src[i] * wr[i];
  p.X[(cloud * NNODE + node) * SDIM + t] = acc;
}

// ---------------- KNN: 5 smallest d2 (excl self), stable tie-break ----------------
__global__ void knn_kernel(Ptrs p) {
  int i = blockIdx.x, cloud = blockIdx.z;
  int lane = threadIdx.x;                 // 64 threads = 1 wave
  __shared__ float d2s[NNODE];
  const float* X = p.X + cloud * NNODE * SDIM;
  float xi[SDIM];
  for (int t = 0; t < SDIM; ++t) xi[t] = X[i * SDIM + t];
  for (int j = lane; j < NNODE; j += 64) {
    float s = 0.f;
    for (int t = 0; t < SDIM; ++t) { float d = xi[t] - X[j * SDIM + t]; s += d * d; }
    d2s[j] = (j == i) ? 3.4e38f : s;
  }
  __syncthreads();
  for (int r = 0; r < KNN_K; ++r) {
    float bv = 3.39e38f; int bi = NNODE;
    for (int j = lane; j < NNODE; j += 64) {
      float val = d2s[j];
      if (val < bv || (val == bv && j < bi)) { bv = val; bi = j; }
    }
    for (int o = 32; o > 0; o >>= 1) {
      float ov = __shfl_down(bv, o); int oi = __shfl_down(bi, o);
      if (ov < bv || (ov == bv && oi < bi)) { bv = ov; bi = oi; }
    }
    if (lane == 0) {
      p.nn[(cloud * NNODE + i) * KNN_K + r] = bi;
      d2s[bi] = 3.4e38f;
    }
    __syncthreads();
  }
}

// ---------------- symmetrized adjacency -> per-node neighbor lists ----------------
__global__ void adj_kernel(Ptrs p) {
  int idx = blockIdx.x * 256 + threadIdx.x;
  if (idx >= 2 * NNODE) return;
  int cloud = idx >> 9, i = idx & 511;
  const int* nn = p.nn + cloud * NNODE * KNN_K;
  int c = 0;
  for (int j = 0; j < NNODE; ++j) {
    if (j == i) continue;
    bool e = false;
    for (int r = 0; r < KNN_K; ++r)
      if (nn[i * KNN_K + r] == j || nn[j * KNN_K + r] == i) e = true;
    if (e) { if (c < MAXNBR) p.nbr[(cloud * NNODE + i) * MAXNBR + c] = j; ++c; }
  }
  p.cnt[cloud * NNODE + i] = (c > MAXNBR ? MAXNBR : c);
}

// ---------------- dense assembly of L ----------------
// off-block (i,j) = alpha*u u^T - I ;  diag(i) = deg_i*I - sum_{k<i} beta*u u^T
__global__ void assemble_kernel(Ptrs p, int cloud0) {
  int i = blockIdx.x;
  int cloud = cloud0 + blockIdx.z;
  float* A = matA(p, cloud);
  const float* X = p.X + cloud * NNODE * SDIM;
  const int* nbr = p.nbr + (cloud * NNODE + i) * MAXNBR;
  int cnt = p.cnt[cloud * NNODE + i];
  int tid = threadIdx.x;

  // zero this node's 8 rows
  for (int idx = tid; idx < SDIM * NLS; idx += 256) {
    int t = idx >> 12;
    int c = idx & 4095;
    A[(size_t)(i * SDIM + t) * NLS + c] = 0.f;
  }
  __shared__ float diag[64];
  __shared__ float xi[SDIM];
  if (tid < SDIM) xi[tid] = X[i * SDIM + tid];
  if (tid < 64)   diag[tid] = 0.f;
  __syncthreads();

  for (int s = 0; s < cnt; ++s) {
    int j = nbr[s];
    float d[SDIM], ss = 0.f;
    for (int t = 0; t < SDIM; ++t) { d[t] = X[j * SDIM + t] - xi[t]; ss += d[t] * d[t]; }
    float dn = sqrtf(ss) + 1e-12f;
    float alpha = dn < 1.f ? dn : 1.f;
    float inv = 1.f / dn;
    if (tid < 64) {
      int t = tid >> 3, t2 = tid & 7;
      float ut = d[t] * inv, ut2 = d[t2] * inv;
      A[(size_t)(i * SDIM + t) * NLS + j * SDIM + t2] =
          alpha * ut * ut2 - (t == t2 ? 1.f : 0.f);
      if (j < i) {
        float beta = 2.f * alpha - alpha * alpha;
        diag[tid] += beta * ut * ut2;
      }
    }
  }
  __syncthreads();
  if (tid < 64) {
    int t = tid >> 3, t2 = tid & 7;
    A[(size_t)(i * SDIM + t) * NLS + i * SDIM + t2] =
        (t == t2 ? (float)cnt : 0.f) - diag[tid];
  }
}

// ---------------- Householder step part 1: build v (from symmetric row k), w = A_t v ----------------
__global__ void k2_house_symv(Ptrs p, int k, int cloud0) {
  int cloud = cloud0 + blockIdx.z;
  float* A = matA(p, cloud);
  const int n = NLS;
  const int m = n - k - 1;
  int tid = threadIdx.x, lane = tid & 63, wv = tid >> 6;
  __shared__ float vlds[NLS];
  __shared__ float red[4];

  // Phase A (redundant per wg): load row k (== column k by symmetry), sumsq
  const float* rowk = A + (size_t)k * n;
  float part = 0.f;
  for (int idx = tid; idx < m; idx += 256) {
    float val = rowk[k + 1 + idx];
    vlds[idx] = val;
    part += val * val;
  }
  for (int o = 32; o > 0; o >>= 1) part += __shfl_down(part, o);
  if (lane == 0) red[wv] = part;
  __syncthreads();
  float sumsq = red[0] + red[1] + red[2] + red[3];
  float x0 = vlds[0];
  float sgn = (x0 >= 0.f) ? 1.f : -1.f;
  float sigma = sqrtf(sumsq);
  bool  ok   = sigma > 1e-30f;
  float beta_ = ok ? 1.f / (sigma * (sigma + fabsf(x0))) : 0.f;
  float eval  = ok ? -sgn * sigma : 0.f;
  if (tid == 0 && ok) vlds[0] = x0 + sgn * sigma;
  __syncthreads();

  // Phase B: w = A_trail * v   (rows strided by wave)
  int nwaves = gridDim.x * 4;
  int gw = blockIdx.x * 4 + wv;
  float vtwloc = 0.f;
  for (int ro = gw; ro < m; ro += nwaves) {
    int r = k + 1 + ro;
    const float* rowr = A + (size_t)r * n;
    float acc = 0.f;
    for (int c = lane; c < m; c += 64) acc += rowr[k + 1 + c] * vlds[c];
    for (int o = 32; o > 0; o >>= 1) acc += __shfl_down(acc, o);
    if (lane == 0) {
      p.w[cloud * NLS + r] = acc;
      vtwloc += vlds[ro] * acc;
    }
  }
  if (lane == 0) atomicAdd(&p.vtw[cloud * NLS + k], vtwloc);

  if (blockIdx.x == 0) {
    for (int idx = tid; idx < m; idx += 256)
      p.v[cloud * NLS + k + 1 + idx] = vlds[idx];
    if (tid == 0) {
      p.ebuf[cloud * NLS + k] = eval;
      p.bta [cloud * NLS + k] = beta_;
    }
  }
}

// ---------------- Householder step part 2: rank-2 trailing update ----------------
// A -= v w2^T + w2 v^T,  w2 = beta*w - 0.5*beta^2*(v^T w)*v
__global__ void k3_update(Ptrs p, int k, int cloud0) {
  int cloud = cloud0 + blockIdx.z;
  float* A = matA(p, cloud);
  const int n = NLS;
  int r = k + 1 + blockIdx.y;
  int c = k + 1 + blockIdx.x * 256 + threadIdx.x;
  if (c >= n) return;
  float beta_ = p.bta[cloud * NLS + k];
  float vtw   = p.vtw[cloud * NLS + k];
  float s = 0.5f * beta_ * beta_ * vtw;
  float vr = p.v[cloud * NLS + r], vc = p.v[cloud * NLS + c];
  float wr = p.w[cloud * NLS + r], wc = p.w[cloud * NLS + c];
  float w2r = beta_ * wr - s * vr;
  float w2c = beta_ * wc - s * vc;
  A[(size_t)r * n + c] -= vr * w2c + w2r * vc;
}

// ---------------- gather tridiagonal + Gershgorin bounds ----------------
__global__ void gather_kernel(Ptrs p, int cloud0) {
  int cloud = cloud0 + blockIdx.z;
  float* A = matA(p, cloud);
  const int n = NLS;
  int tid = threadIdx.x;   // 1024
  float* d  = p.darr + cloud * NLS;
  float* e2 = p.e2   + cloud * NLS;
  __shared__ float elds[NLS];
  for (int i = tid; i < n; i += 1024) {
    d[i] = A[(size_t)i * n + i];
    float e = (i < n - 2) ? p.ebuf[cloud * NLS + i]
            : ((i == n - 2) ? A[(size_t)(n - 1) * n + (n - 2)] : 0.f);
    e2[i]   = e * e;
    elds[i] = fabsf(e);
  }
  __syncthreads();
  float lo = 3.4e38f, hi = -3.4e38f;
  for (int i = tid; i < n; i += 1024) {
    float rad = elds[i] + (i > 0 ? elds[i - 1] : 0.f);
    lo = fminf(lo, d[i] - rad);
    hi = fmaxf(hi, d[i] + rad);
  }
  __shared__ float rl[16], rh[16];
  int lane = tid & 63, wv = tid >> 6;
  for (int o = 32; o > 0; o >>= 1) {
    lo = fminf(lo, __shfl_down(lo, o));
    hi = fmaxf(hi, __shfl_down(hi, o));
  }
  if (lane == 0) { rl[wv] = lo; rh[wv] = hi; }
  __syncthreads();
  if (tid == 0) {
    for (int t = 1; t < 16; ++t) { lo = fminf(lo, rl[t]); hi = fmaxf(hi, rh[t]); }
    p.bounds[cloud * 2 + 0] = lo - 0.5f;
    p.bounds[cloud * 2 + 1] = hi + 0.5f;
  }
}

// ---------------- bisection (Sturm count, LAPACK dstebz recurrence) ----------------
__global__ void bisect_kernel(Ptrs p, int cloud0) {
  int cloud = cloud0 + blockIdx.z;
  int idx = blockIdx.x * 256 + threadIdx.x;   // eigenvalue index, 0..4095
  const float* d  = p.darr + cloud * NLS;
  const float* e2 = p.e2   + cloud * NLS;
  float lo = p.bounds[cloud * 2 + 0];
  float hi = p.bounds[cloud * 2 + 1];
  const float pivmin = 1e-28f;
  for (int it = 0; it < 34; ++it) {
    float mid = 0.5f * (lo + hi);
    int cnt = 0;
    float qq = d[0] - mid;
    if (fabsf(qq) < pivmin) qq = -pivmin;
    cnt += (qq < 0.f);
    for (int i = 1; i < NLS; ++i) {
      qq = d[i] - mid - e2[i - 1] / qq;
      if (fabsf(qq) < pivmin) qq = -pivmin;
      cnt += (qq < 0.f);
    }
    if (cnt > idx) hi = mid; else lo = mid;
  }
  float ev = 0.5f * (lo + hi);
  p.eigs[cloud * NLS + idx] = ev > 0.f ? ev : 0.f;
}

// ---------------- final: gated spectral gaps -> scalar ----------------
__global__ void final_kernel(Ptrs p, float* out) {
  __shared__ float lds[64];
  int tid = threadIdx.x;   // 256
  for (int cloud = 0; cloud < 2; ++cloud) {
    float num = 0.f, den = 0.f;
    for (int i = tid; i < NLS; i += 256) {
      float lam = p.eigs[cloud * NLS + i];
      float g = 1.f / (1.f + expf(-(lam - 1e-4f) * 100.f));  // sigmoid((l-eps)/tau)
      num += lam * g;
      den += g;
    }
    for (int o = 32; o > 0; o >>= 1) {
      num += __shfl_down(num, o);
      den += __shfl_down(den, o);
    }
    if ((tid & 63) == 0) { lds[(tid >> 6) * 2] = num; lds[(tid >> 6) * 2 + 1] = den; }
    __syncthreads();
    if (tid == 0) {
      float N = lds[0] + lds[2] + lds[4] + lds[6];
      float D = lds[1] + lds[3] + lds[5] + lds[7];
      lds[32 + cloud] = N / (D + 1e-12f);
    }
    __syncthreads();
  }
  if (tid == 0) {
    float gp = lds[32], gn = lds[33];
    float trip = gp - gn + 0.5f;
    if (trip < 0.f) trip = 0.f;
    out[0] = trip + 0.1f * gp;
  }
}

extern "C" void kernel_launch(void* const* d_in, const int* in_sizes, int n_in,
                              void* d_out, int out_size, void* d_ws, size_t ws_size,
                              hipStream_t stream) {
  const float* q  = (const float*)d_in[0];
  const float* pe = (const float*)d_in[1];
  const float* ne = (const float*)d_in[2];
  const float* W  = (const float*)d_in[3];

  char* base = (char*)d_ws;
  size_t off = 0;
  auto alloc = [&](size_t nbytes) -> void* {
    off = (off + 255) & ~(size_t)255;
    void* r = base + off;
    off += nbytes;
    return r;
  };

  Ptrs p;
  p.X      = (float*)alloc(sizeof(float) * 2 * NNODE * SDIM);
  p.nn     = (int*)  alloc(sizeof(int)   * 2 * NNODE * KNN_K);
  p.nbr    = (int*)  alloc(sizeof(int)   * 2 * NNODE * MAXNBR);
  p.cnt    = (int*)  alloc(sizeof(int)   * 2 * NNODE);
  p.v      = (float*)alloc(sizeof(float) * 2 * NLS);
  p.w      = (float*)alloc(sizeof(float) * 2 * NLS);
  p.ebuf   = (float*)alloc(sizeof(float) * 2 * NLS);
  p.bta    = (float*)alloc(sizeof(float) * 2 * NLS);
  p.vtw    = (float*)alloc(sizeof(float) * 2 * NLS);
  p.darr   = (float*)alloc(sizeof(float) * 2 * NLS);
  p.e2     = (float*)alloc(sizeof(float) * 2 * NLS);
  p.bounds = (float*)alloc(sizeof(float) * 4);
  p.eigs   = (float*)alloc(sizeof(float) * 2 * NLS);

  const size_t Abytes = (size_t)NLS * NLS * sizeof(float);
  p.A0 = (float*)alloc(Abytes);
  size_t offA1 = (off + 255) & ~(size_t)255;
  bool batched = (offA1 + Abytes) <= ws_size;
  p.A1 = batched ? (float*)alloc(Abytes) : p.A0;

  // ---- shared preamble ----
  zero_kernel<<<dim3((2 * NLS + 255) / 256), 256, 0, stream>>>(p.vtw, 2 * NLS);
  proj_kernel<<<dim3(32), 256, 0, stream>>>(p, q, pe, ne, W);
  knn_kernel<<<dim3(NNODE, 1, 2), 64, 0, stream>>>(p);
  adj_kernel<<<dim3(4), 256, 0, stream>>>(p);

  auto run_cloud = [&](int cloud0, int z) {
    assemble_kernel<<<dim3(NNODE, 1, z), 256, 0, stream>>>(p, cloud0);
    for (int k = 0; k < NLS - 2; ++k) {
      int m = NLS - k - 1;
      int nwg = (m + 15) / 16; if (nwg > 256) nwg = 256;
      k2_house_symv<<<dim3(nwg, 1, z), 256, 0, stream>>>(p, k, cloud0);
      int cb = (m + 255) / 256;
      k3_update<<<dim3(cb, m, z), 256, 0, stream>>>(p, k, cloud0);
    }
    gather_kernel<<<dim3(1, 1, z), 1024, 0, stream>>>(p, cloud0);
    bisect_kernel<<<dim3(NLS / 256, 1, z), 256, 0, stream>>>(p, cloud0);
  };

  if (batched) {
    run_cloud(0, 2);          // both clouds per launch via blockIdx.z
  } else {
    run_cloud(0, 1);          // A buffer shared: finish cloud 0, then cloud 1
    run_cloud(1, 1);
  }

  final_kernel<<<dim3(1), 256, 0, stream>>>(p, (float*)d_out);
}

// Round 2
// 221529.297 us; speedup vs baseline: 1.2527x; 1.2527x over previous
//
#include <hip/hip_runtime.h>
#include <math.h>

#define NLS    4096   // 512 nodes * 8 stalk dims
#define NNODE  512
#define SDIM   8
#define KNN_K  5
#define MAXNBR 128
#define DIN    768
#define NB     32     // panel width

struct Ptrs {
  float* X;      // [2][NNODE][SDIM]
  int*   nn;     // [2][NNODE][KNN_K]
  int*   nbr;    // [2][NNODE][MAXNBR]
  int*   cnt;    // [2][NNODE]
  float* v;      // [2][NLS]   current Householder vector (flat, global row index)
  float* w;      // [2][NLS]   y = A_trail * v
  float* ebuf;   // [2][NLS]   off-diagonal e[k]
  float* bta;    // [2][NLS]   tau[k]
  float* vtw;    // [2][NLS]   v^T y accumulators (zeroed at start)
  float* darr;   // [2][NLS]   diagonal d[k]
  float* e2;     // [2][NLS]
  float* bounds; // [2][2]
  float* eigs;   // [2][NLS]
  float* Vt;     // [2][NB][NLS]  panel V, transposed layout
  float* Wt;     // [2][NB][NLS]  panel W, transposed layout
  float* c1;     // [2][NB]
  float* c2;     // [2][NB]
  float* A0;
  float* A1;
};

__device__ __forceinline__ float* matA(const Ptrs& p, int cloud) {
  return cloud == 0 ? p.A0 : p.A1;
}

// ---------------- zero helper ----------------
__global__ void zero_kernel(float* ptr, int n) {
  int i = blockIdx.x * 256 + threadIdx.x;
  if (i < n) ptr[i] = 0.f;
}

// ---------------- projection: X = emb @ W^T ----------------
__global__ void proj_kernel(Ptrs p, const float* q, const float* pe,
                            const float* ne, const float* W) {
  int idx = blockIdx.x * 256 + threadIdx.x;   // 2*512*8 = 8192
  if (idx >= 2 * NNODE * SDIM) return;
  int cloud = idx >> 12;
  int rem   = idx & 4095;
  int node  = rem >> 3, t = rem & 7;
  const float* src = (node < 256) ? (q + (size_t)node * DIN)
                                  : ((cloud == 0 ? pe : ne) + (size_t)(node - 256) * DIN);
  const float* wr = W + (size_t)t * DIN;
  float acc = 0.f;
  for (int i = 0; i < DIN; ++i) acc += src[i] * wr[i];
  p.X[(cloud * NNODE + node) * SDIM + t] = acc;
}

// ---------------- KNN ----------------
__global__ void knn_kernel(Ptrs p) {
  int i = blockIdx.x, cloud = blockIdx.z;
  int lane = threadIdx.x;                 // 64 threads = 1 wave
  __shared__ float d2s[NNODE];
  const float* X = p.X + cloud * NNODE * SDIM;
  float xi[SDIM];
  for (int t = 0; t < SDIM; ++t) xi[t] = X[i * SDIM + t];
  for (int j = lane; j < NNODE; j += 64) {
    float s = 0.f;
    for (int t = 0; t < SDIM; ++t) { float d = xi[t] - X[j * SDIM + t]; s += d * d; }
    d2s[j] = (j == i) ? 3.4e38f : s;
  }
  __syncthreads();
  for (int r = 0; r < KNN_K; ++r) {
    float bv = 3.39e38f; int bi = NNODE;
    for (int j = lane; j < NNODE; j += 64) {
      float val = d2s[j];
      if (val < bv || (val == bv && j < bi)) { bv = val; bi = j; }
    }
    for (int o = 32; o > 0; o >>= 1) {
      float ov = __shfl_down(bv, o); int oi = __shfl_down(bi, o);
      if (ov < bv || (ov == bv && oi < bi)) { bv = ov; bi = oi; }
    }
    if (lane == 0) {
      p.nn[(cloud * NNODE + i) * KNN_K + r] = bi;
      d2s[bi] = 3.4e38f;
    }
    __syncthreads();
  }
}

// ---------------- symmetrized adjacency ----------------
__global__ void adj_kernel(Ptrs p) {
  int idx = blockIdx.x * 256 + threadIdx.x;
  if (idx >= 2 * NNODE) return;
  int cloud = idx >> 9, i = idx & 511;
  const int* nn = p.nn + cloud * NNODE * KNN_K;
  int c = 0;
  for (int j = 0; j < NNODE; ++j) {
    if (j == i) continue;
    bool e = false;
    for (int r = 0; r < KNN_K; ++r)
      if (nn[i * KNN_K + r] == j || nn[j * KNN_K + r] == i) e = true;
    if (e) { if (c < MAXNBR) p.nbr[(cloud * NNODE + i) * MAXNBR + c] = j; ++c; }
  }
  p.cnt[cloud * NNODE + i] = (c > MAXNBR ? MAXNBR : c);
}

// ---------------- dense assembly of L ----------------
__global__ void assemble_kernel(Ptrs p, int cloud0) {
  int i = blockIdx.x;
  int cloud = cloud0 + blockIdx.z;
  float* A = matA(p, cloud);
  const float* X = p.X + cloud * NNODE * SDIM;
  const int* nbr = p.nbr + (cloud * NNODE + i) * MAXNBR;
  int cnt = p.cnt[cloud * NNODE + i];
  int tid = threadIdx.x;

  for (int idx = tid; idx < SDIM * NLS; idx += 256) {
    int t = idx >> 12;
    int c = idx & 4095;
    A[(size_t)(i * SDIM + t) * NLS + c] = 0.f;
  }
  __shared__ float diag[64];
  __shared__ float xi[SDIM];
  if (tid < SDIM) xi[tid] = X[i * SDIM + tid];
  if (tid < 64)   diag[tid] = 0.f;
  __syncthreads();

  for (int s = 0; s < cnt; ++s) {
    int j = nbr[s];
    float d[SDIM], ss = 0.f;
    for (int t = 0; t < SDIM; ++t) { d[t] = X[j * SDIM + t] - xi[t]; ss += d[t] * d[t]; }
    float dn = sqrtf(ss) + 1e-12f;
    float alpha = dn < 1.f ? dn : 1.f;
    float inv = 1.f / dn;
    if (tid < 64) {
      int t = tid >> 3, t2 = tid & 7;
      float ut = d[t] * inv, ut2 = d[t2] * inv;
      A[(size_t)(i * SDIM + t) * NLS + j * SDIM + t2] =
          alpha * ut * ut2 - (t == t2 ? 1.f : 0.f);
      if (j < i) {
        float beta = 2.f * alpha - alpha * alpha;
        diag[tid] += beta * ut * ut2;
      }
    }
  }
  __syncthreads();
  if (tid < 64) {
    int t = tid >> 3, t2 = tid & 7;
    A[(size_t)(i * SDIM + t) * NLS + i * SDIM + t2] =
        (t == t2 ? (float)cnt : 0.f) - diag[tid];
  }
}

// ---------------- KA: panel-corrected column + Householder + panel dots ----------------
// single workgroup of 1024 threads, grid (1,1,z)
__global__ void ka_kernel(Ptrs p, int k, int j, int cloud0) {
  int cloud = cloud0 + blockIdx.z;
  const float* A = matA(p, cloud);
  float* Vt = p.Vt + (size_t)cloud * NB * NLS;
  float* Wt = p.Wt + (size_t)cloud * NB * NLS;
  int tid = threadIdx.x, lane = tid & 63, wv = tid >> 6;   // 16 waves
  int m1 = NLS - k;                 // a[i] <-> global col k+i
  __shared__ float a[NLS];
  __shared__ float vk[NB], wk[NB];
  __shared__ float red[16];
  __shared__ float bcast[4];        // beta, tau, scale, alpha

  if (tid < j) { vk[tid] = Vt[(size_t)tid * NLS + k]; wk[tid] = Wt[(size_t)tid * NLS + k]; }
  __syncthreads();

  const float* rowk = A + (size_t)k * NLS + k;
  for (int i = tid; i < m1; i += 1024) {
    float val = rowk[i];
    int r = k + i;
    for (int j2 = 0; j2 < j; ++j2)
      val -= Vt[(size_t)j2 * NLS + r] * wk[j2] + Wt[(size_t)j2 * NLS + r] * vk[j2];
    a[i] = val;
  }
  __syncthreads();

  float part = 0.f;
  for (int i = tid; i < m1; i += 1024) if (i >= 2) part += a[i] * a[i];
  for (int o = 32; o > 0; o >>= 1) part += __shfl_down(part, o);
  if (lane == 0) red[wv] = part;
  __syncthreads();
  if (tid == 0) {
    float xnorm2 = 0.f;
    for (int t = 0; t < 16; ++t) xnorm2 += red[t];
    float alpha = a[1];
    float beta, tau, scale;
    if (xnorm2 > 0.f) {
      beta  = -copysignf(sqrtf(alpha * alpha + xnorm2), alpha);
      tau   = (beta - alpha) / beta;
      scale = 1.f / (alpha - beta);
    } else { beta = alpha; tau = 0.f; scale = 0.f; }
    bcast[0] = beta; bcast[1] = tau; bcast[2] = scale;
    p.darr[cloud * NLS + k] = a[0];
    p.ebuf[cloud * NLS + k] = beta;
    p.bta [cloud * NLS + k] = tau;
  }
  __syncthreads();
  float scale = bcast[2];

  float* vflat = p.v + cloud * NLS;
  for (int i = tid; i < m1; i += 1024) {
    if (i >= 1) {
      float v = (i == 1) ? 1.f : a[i] * scale;
      a[i] = v;
      Vt[(size_t)j * NLS + (k + i)] = v;
      vflat[k + i] = v;
    }
  }
  __syncthreads();

  // c1[j2] = W[:,j2]^T v,  c2[j2] = V[:,j2]^T v  (wave wv handles j2 = wv mod 16)
  for (int j2 = wv; j2 < j; j2 += 16) {
    float s1 = 0.f, s2 = 0.f;
    for (int i = 1 + lane; i < m1; i += 64) {
      float v = a[i]; int r = k + i;
      s1 += Wt[(size_t)j2 * NLS + r] * v;
      s2 += Vt[(size_t)j2 * NLS + r] * v;
    }
    for (int o = 32; o > 0; o >>= 1) {
      s1 += __shfl_down(s1, o);
      s2 += __shfl_down(s2, o);
    }
    if (lane == 0) { p.c1[cloud * NB + j2] = s1; p.c2[cloud * NB + j2] = s2; }
  }
}

// ---------------- KW1: y = A_trail * v  (heavy GEMV) + v^T y ----------------
__global__ void kw1_kernel(Ptrs p, int k, int cloud0) {
  int cloud = cloud0 + blockIdx.z;
  const float* A = matA(p, cloud);
  int m = NLS - k - 1;
  int tid = threadIdx.x, lane = tid & 63, wv = tid >> 6;
  __shared__ float vlds[NLS];
  const float* vsrc = p.v + cloud * NLS + k + 1;
  for (int i = tid; i < m; i += 256) vlds[i] = vsrc[i];
  __syncthreads();
  int nwaves = gridDim.x * 4;
  int gw = blockIdx.x * 4 + wv;
  float vtwloc = 0.f;
  for (int ro = gw; ro < m; ro += nwaves) {
    int r = k + 1 + ro;
    const float* rowr = A + (size_t)r * NLS + k + 1;
    float acc = 0.f;
    for (int c = lane; c < m; c += 64) acc += rowr[c] * vlds[c];
    for (int o = 32; o > 0; o >>= 1) acc += __shfl_down(acc, o);
    if (lane == 0) {
      p.w[cloud * NLS + r] = acc;
      vtwloc += vlds[ro] * acc;
    }
  }
  if (lane == 0) atomicAdd(&p.vtw[cloud * NLS + k], vtwloc);
}

// ---------------- KW2: w = tau*(y - V c1 - W c2) - 0.5*tau*(w'^T v)*v ----------------
__global__ void kw2_kernel(Ptrs p, int k, int j, int cloud0) {
  int cloud = cloud0 + blockIdx.z;
  int m = NLS - k - 1;
  int idx = blockIdx.x * 256 + threadIdx.x;
  if (idx >= m) return;
  int r = k + 1 + idx;
  float tau = p.bta[cloud * NLS + k];
  float vty = p.vtw[cloud * NLS + k];
  const float* c1 = p.c1 + cloud * NB;
  const float* c2 = p.c2 + cloud * NB;
  float dotc = 0.f;
  for (int j2 = 0; j2 < j; ++j2) dotc += c1[j2] * c2[j2];
  float s = tau * (vty - 2.f * dotc);
  const float* Vt = p.Vt + (size_t)cloud * NB * NLS;
  float*       Wt = p.Wt + (size_t)cloud * NB * NLS;
  float y = p.w[cloud * NLS + r];
  float corr = 0.f;
  for (int j2 = 0; j2 < j; ++j2)
    corr += Vt[(size_t)j2 * NLS + r] * c1[j2] + Wt[(size_t)j2 * NLS + r] * c2[j2];
  float v = Vt[(size_t)j * NLS + r];
  float w = tau * y - tau * corr - 0.5f * tau * s * v;
  Wt[(size_t)j * NLS + r] = w;
}

// ---------------- KUPD: A_trail -= V W^T + W V^T (rank-2*NB), 64x64 tiles ----------------
__global__ void kupd_kernel(Ptrs p, int k0, int cloud0) {
  int cloud = cloud0 + blockIdx.z;
  float* A = matA(p, cloud);
  const float* Vt = p.Vt + (size_t)cloud * NB * NLS;
  const float* Wt = p.Wt + (size_t)cloud * NB * NLS;
  int base = k0 + NB;
  int r0 = base + blockIdx.y * 64, c0 = base + blockIdx.x * 64;
  __shared__ float Vr[NB][64], Wr[NB][64], Vc[NB][64], Wc[NB][64];
  int tid = threadIdx.x;
  for (int idx = tid; idx < NB * 64; idx += 256) {
    int j = idx >> 6, i = idx & 63;
    int r = r0 + i, c = c0 + i;
    Vr[j][i] = (r < NLS) ? Vt[(size_t)j * NLS + r] : 0.f;
    Wr[j][i] = (r < NLS) ? Wt[(size_t)j * NLS + r] : 0.f;
    Vc[j][i] = (c < NLS) ? Vt[(size_t)j * NLS + c] : 0.f;
    Wc[j][i] = (c < NLS) ? Wt[(size_t)j * NLS + c] : 0.f;
  }
  __syncthreads();
  int ty = tid >> 4, tx = tid & 15;   // 16x16 threads, 4x4 elems each
  float acc[4][4] = {{0.f}};
  for (int j = 0; j < NB; ++j) {
    float vr[4], wr[4], vc[4], wc[4];
    for (int a = 0; a < 4; ++a) {
      vr[a] = Vr[j][ty * 4 + a]; wr[a] = Wr[j][ty * 4 + a];
      vc[a] = Vc[j][tx * 4 + a]; wc[a] = Wc[j][tx * 4 + a];
    }
    for (int a = 0; a < 4; ++a)
      for (int b = 0; b < 4; ++b)
        acc[a][b] += vr[a] * wc[b] + wr[a] * vc[b];
  }
  for (int a = 0; a < 4; ++a) {
    int r = r0 + ty * 4 + a;
    int c = c0 + tx * 4;
    if (r < NLS && c < NLS) {
      float4* pa = (float4*)&A[(size_t)r * NLS + c];
      float4 old = *pa;
      old.x -= acc[a][0]; old.y -= acc[a][1];
      old.z -= acc[a][2]; old.w -= acc[a][3];
      *pa = old;
    }
  }
}

// ---------------- trailing 64x64 block: in-LDS tridiagonalization ----------------
__global__ void ktrail_kernel(Ptrs p, int cloud0) {
  int cloud = cloud0 + blockIdx.z;
  float* A = matA(p, cloud);
  const int base = NLS - 64;
  int lane = threadIdx.x;  // 64 threads
  __shared__ float B[64][65];
  __shared__ float vv[64], ww[64];
  for (int r = 0; r < 64; ++r)
    B[r][lane] = A[(size_t)(base + r) * NLS + base + lane];
  __syncthreads();
  for (int kl = 0; kl <= 61; ++kl) {
    float val = (lane >= kl + 2) ? B[kl][lane] : 0.f;
    float part = val * val;
    for (int o = 32; o > 0; o >>= 1) part += __shfl_xor(part, o);
    float xnorm2 = part;
    float alpha = B[kl][kl + 1];
    float beta, tau, scale;
    if (xnorm2 > 0.f) {
      beta  = -copysignf(sqrtf(alpha * alpha + xnorm2), alpha);
      tau   = (beta - alpha) / beta;
      scale = 1.f / (alpha - beta);
    } else { beta = alpha; tau = 0.f; scale = 0.f; }
    if (lane == 0) {
      p.darr[cloud * NLS + base + kl] = B[kl][kl];
      p.ebuf[cloud * NLS + base + kl] = beta;
    }
    vv[lane] = (lane == kl + 1) ? 1.f : ((lane >= kl + 2) ? B[kl][lane] * scale : 0.f);
    __syncthreads();
    float y = 0.f;
    if (lane >= kl + 1)
      for (int c = kl + 1; c < 64; ++c) y += B[lane][c] * vv[c];
    float vy = (lane >= kl + 1) ? vv[lane] * y : 0.f;
    for (int o = 32; o > 0; o >>= 1) vy += __shfl_xor(vy, o);
    float w = tau * y - 0.5f * tau * (tau * vy) * vv[lane];
    ww[lane] = (lane >= kl + 1) ? w : 0.f;
    __syncthreads();
    if (lane >= kl + 1) {
      float vr = vv[lane], wr = ww[lane];
      for (int c = kl + 1; c < 64; ++c)
        B[lane][c] -= vr * ww[c] + wr * vv[c];
    }
    __syncthreads();
  }
  if (lane == 0) {
    p.darr[cloud * NLS + base + 62] = B[62][62];
    p.darr[cloud * NLS + base + 63] = B[63][63];
    p.ebuf[cloud * NLS + base + 62] = B[63][62];
    p.ebuf[cloud * NLS + base + 63] = 0.f;
  }
}

// ---------------- gather tridiagonal (from darr/ebuf) + Gershgorin bounds ----------------
__global__ void gather_kernel(Ptrs p, int cloud0) {
  int cloud = cloud0 + blockIdx.z;
  const int n = NLS;
  int tid = threadIdx.x;   // 1024
  const float* d = p.darr + cloud * NLS;
  float* e2 = p.e2 + cloud * NLS;
  __shared__ float elds[NLS];
  for (int i = tid; i < n; i += 1024) {
    float e = (i < n - 1) ? p.ebuf[cloud * NLS + i] : 0.f;
    e2[i]   = e * e;
    elds[i] = fabsf(e);
  }
  __syncthreads();
  float lo = 3.4e38f, hi = -3.4e38f;
  for (int i = tid; i < n; i += 1024) {
    float rad = elds[i] + (i > 0 ? elds[i - 1] : 0.f);
    lo = fminf(lo, d[i] - rad);
    hi = fmaxf(hi, d[i] + rad);
  }
  __shared__ float rl[16], rh[16];
  int lane = tid & 63, wv = tid >> 6;
  for (int o = 32; o > 0; o >>= 1) {
    lo = fminf(lo, __shfl_down(lo, o));
    hi = fmaxf(hi, __shfl_down(hi, o));
  }
  if (lane == 0) { rl[wv] = lo; rh[wv] = hi; }
  __syncthreads();
  if (tid == 0) {
    for (int t = 1; t < 16; ++t) { lo = fminf(lo, rl[t]); hi = fmaxf(hi, rh[t]); }
    p.bounds[cloud * 2 + 0] = lo - 0.5f;
    p.bounds[cloud * 2 + 1] = hi + 0.5f;
  }
}

// ---------------- bisection ----------------
__global__ void bisect_kernel(Ptrs p, int cloud0) {
  int cloud = cloud0 + blockIdx.z;
  int idx = blockIdx.x * 256 + threadIdx.x;
  const float* d  = p.darr + cloud * NLS;
  const float* e2 = p.e2   + cloud * NLS;
  float lo = p.bounds[cloud * 2 + 0];
  float hi = p.bounds[cloud * 2 + 1];
  const float pivmin = 1e-28f;
  for (int it = 0; it < 34; ++it) {
    float mid = 0.5f * (lo + hi);
    int cnt = 0;
    float qq = d[0] - mid;
    if (fabsf(qq) < pivmin) qq = -pivmin;
    cnt += (qq < 0.f);
    for (int i = 1; i < NLS; ++i) {
      qq = d[i] - mid - e2[i - 1] / qq;
      if (fabsf(qq) < pivmin) qq = -pivmin;
      cnt += (qq < 0.f);
    }
    if (cnt > idx) hi = mid; else lo = mid;
  }
  float ev = 0.5f * (lo + hi);
  p.eigs[cloud * NLS + idx] = ev > 0.f ? ev : 0.f;
}

// ---------------- final ----------------
__global__ void final_kernel(Ptrs p, float* out) {
  __shared__ float lds[64];
  int tid = threadIdx.x;   // 256
  for (int cloud = 0; cloud < 2; ++cloud) {
    float num = 0.f, den = 0.f;
    for (int i = tid; i < NLS; i += 256) {
      float lam = p.eigs[cloud * NLS + i];
      float g = 1.f / (1.f + expf(-(lam - 1e-4f) * 100.f));
      num += lam * g;
      den += g;
    }
    for (int o = 32; o > 0; o >>= 1) {
      num += __shfl_down(num, o);
      den += __shfl_down(den, o);
    }
    if ((tid & 63) == 0) { lds[(tid >> 6) * 2] = num; lds[(tid >> 6) * 2 + 1] = den; }
    __syncthreads();
    if (tid == 0) {
      float N = lds[0] + lds[2] + lds[4] + lds[6];
      float D = lds[1] + lds[3] + lds[5] + lds[7];
      lds[32 + cloud] = N / (D + 1e-12f);
    }
    __syncthreads();
  }
  if (tid == 0) {
    float gp = lds[32], gn = lds[33];
    float trip = gp - gn + 0.5f;
    if (trip < 0.f) trip = 0.f;
    out[0] = trip + 0.1f * gp;
  }
}

extern "C" void kernel_launch(void* const* d_in, const int* in_sizes, int n_in,
                              void* d_out, int out_size, void* d_ws, size_t ws_size,
                              hipStream_t stream) {
  const float* q  = (const float*)d_in[0];
  const float* pe = (const float*)d_in[1];
  const float* ne = (const float*)d_in[2];
  const float* W  = (const float*)d_in[3];

  char* base = (char*)d_ws;
  size_t off = 0;
  auto alloc = [&](size_t nbytes) -> void* {
    off = (off + 255) & ~(size_t)255;
    void* r = base + off;
    off += nbytes;
    return r;
  };

  Ptrs p;
  p.X      = (float*)alloc(sizeof(float) * 2 * NNODE * SDIM);
  p.nn     = (int*)  alloc(sizeof(int)   * 2 * NNODE * KNN_K);
  p.nbr    = (int*)  alloc(sizeof(int)   * 2 * NNODE * MAXNBR);
  p.cnt    = (int*)  alloc(sizeof(int)   * 2 * NNODE);
  p.v      = (float*)alloc(sizeof(float) * 2 * NLS);
  p.w      = (float*)alloc(sizeof(float) * 2 * NLS);
  p.ebuf   = (float*)alloc(sizeof(float) * 2 * NLS);
  p.bta    = (float*)alloc(sizeof(float) * 2 * NLS);
  p.vtw    = (float*)alloc(sizeof(float) * 2 * NLS);
  p.darr   = (float*)alloc(sizeof(float) * 2 * NLS);
  p.e2     = (float*)alloc(sizeof(float) * 2 * NLS);
  p.bounds = (float*)alloc(sizeof(float) * 4);
  p.eigs   = (float*)alloc(sizeof(float) * 2 * NLS);
  p.Vt     = (float*)alloc(sizeof(float) * 2 * NB * NLS);
  p.Wt     = (float*)alloc(sizeof(float) * 2 * NB * NLS);
  p.c1     = (float*)alloc(sizeof(float) * 2 * NB);
  p.c2     = (float*)alloc(sizeof(float) * 2 * NB);

  const size_t Abytes = (size_t)NLS * NLS * sizeof(float);
  p.A0 = (float*)alloc(Abytes);
  size_t offA1 = (off + 255) & ~(size_t)255;
  bool batched = (offA1 + Abytes) <= ws_size;
  p.A1 = batched ? (float*)alloc(Abytes) : p.A0;

  // ---- shared preamble ----
  zero_kernel<<<dim3((2 * NLS + 255) / 256), 256, 0, stream>>>(p.vtw, 2 * NLS);
  proj_kernel<<<dim3(32), 256, 0, stream>>>(p, q, pe, ne, W);
  knn_kernel<<<dim3(NNODE, 1, 2), 64, 0, stream>>>(p);
  adj_kernel<<<dim3(4), 256, 0, stream>>>(p);

  auto run_cloud = [&](int cloud0, int z) {
    assemble_kernel<<<dim3(NNODE, 1, z), 256, 0, stream>>>(p, cloud0);
    for (int k0 = 0; k0 + 64 < NLS; k0 += NB) {          // k0 = 0..4000
      for (int j = 0; j < NB; ++j) {
        int k = k0 + j;
        int m = NLS - k - 1;
        ka_kernel<<<dim3(1, 1, z), 1024, 0, stream>>>(p, k, j, cloud0);
        int nwg = (m + 7) / 8; if (nwg > 512) nwg = 512;
        kw1_kernel<<<dim3(nwg, 1, z), 256, 0, stream>>>(p, k, cloud0);
        kw2_kernel<<<dim3((m + 255) / 256, 1, z), 256, 0, stream>>>(p, k, j, cloud0);
      }
      int mprime = NLS - (k0 + NB);
      int nt = (mprime + 63) / 64;
      kupd_kernel<<<dim3(nt, nt, z), 256, 0, stream>>>(p, k0, cloud0);
    }
    ktrail_kernel<<<dim3(1, 1, z), 64, 0, stream>>>(p, cloud0);
    gather_kernel<<<dim3(1, 1, z), 1024, 0, stream>>>(p, cloud0);
    bisect_kernel<<<dim3(NLS / 256, 1, z), 256, 0, stream>>>(p, cloud0);
  };

  if (batched) {
    run_cloud(0, 2);
  } else {
    run_cloud(0, 1);
    run_cloud(1, 1);
  }

  final_kernel<<<dim3(1), 256, 0, stream>>>(p, (float*)d_out);
}